// Round 1
// baseline (273.975 us; speedup 1.0000x reference)
//
#include <hip/hip_runtime.h>
#include <hip/hip_bf16.h>

typedef __attribute__((ext_vector_type(8))) __bf16 bf16x8;
typedef __attribute__((ext_vector_type(4))) float f32x4;
typedef __attribute__((ext_vector_type(8))) unsigned short ushort8;
typedef unsigned short ushort;

__device__ __forceinline__ ushort f2bf(float f) {
    unsigned u = __builtin_bit_cast(unsigned, f);
    unsigned r = (u + 0x7fffu + ((u >> 16) & 1u)) >> 16;
    return (ushort)r;
}

// ---------------------------------------------------------------------------
// Pack layer-1 weights (4x [512,256] fp32) and layer-2 weights into bf16
// MFMA-B-fragment order in ws.
// W1p chunk c = (n16*16 + ksg)*64 + lane ; element e: B[k= ksg*32+(l>>4)*8+e][col=(n16&15)*16+(l&15)] of hypernet j=n16>>4
// W2p chunk c = (f*8 + ks)*64 + lane over 21 n-frags (321 cols padded to 336)
// ---------------------------------------------------------------------------
__global__ __launch_bounds__(256) void k_pack(
    const float* __restrict__ w1a, const float* __restrict__ w1b,
    const float* __restrict__ w1c, const float* __restrict__ w1d,
    const float* __restrict__ w2a, const float* __restrict__ w2b,
    const float* __restrict__ w2c, const float* __restrict__ w2d,
    ushort* __restrict__ W1p, ushort* __restrict__ W2p)
{
    int c = blockIdx.x * 256 + threadIdx.x;
    if (c < 65536) {
        int l = c & 63, ks = (c >> 6) & 15, n16 = c >> 10;
        int j = n16 >> 4;
        int col = (n16 & 15) * 16 + (l & 15);
        int kb = ks * 32 + (l >> 4) * 8;
        const float* W = (j == 0) ? w1a : (j == 1) ? w1b : (j == 2) ? w1c : w1d;
        ushort8 o;
#pragma unroll
        for (int e = 0; e < 8; ++e) o[e] = f2bf(W[(size_t)(kb + e) * 256 + col]);
        *reinterpret_cast<ushort8*>(W1p + (size_t)c * 8) = o;
    } else if (c < 65536 + 10752) {
        int cc = c - 65536;
        int l = cc & 63, ks = (cc >> 6) & 7, f = cc >> 9;
        int colg = f * 16 + (l & 15);
        int kb = ks * 32 + (l >> 4) * 8;
        const float* W = nullptr; int lc = 0, ncols = 1;
        if (colg < 192)        { W = w2a; lc = colg;       ncols = 192; }
        else if (colg < 256)   { W = w2b; lc = colg - 192; ncols = 64; }
        else if (colg < 320)   { W = w2c; lc = colg - 256; ncols = 64; }
        else if (colg == 320)  { W = w2d; lc = 0;          ncols = 1; }
        ushort8 o;
#pragma unroll
        for (int e = 0; e < 8; ++e)
            o[e] = W ? f2bf(W[(size_t)(kb + e) * ncols + lc]) : (ushort)0;
        *reinterpret_cast<ushort8*>(W2p + (size_t)cc * 8) = o;
    }
}

// ---------------------------------------------------------------------------
// Layer-1 GEMM: hid[m][n] = relu( S[m][:] @ W1cat[:,n] + b1cat[n] ), bf16 out.
// 128x128 tile, 256 threads = 4 waves (2x2), each wave 64x64 via 4x4 frags of
// mfma_f32_16x16x32_bf16. A staged fp32->bf16 into XOR-swizzled LDS; B read
// directly from pre-packed ws fragments (coalesced dwordx4/lane, L2-resident).
// grid = (nt=8, mt) so the 8 N-tiles of one S-tile run adjacently (L3 reuse).
// ---------------------------------------------------------------------------
__global__ __launch_bounds__(256) void k_l1(
    const float* __restrict__ S, const ushort* __restrict__ W1p,
    const float* __restrict__ b0, const float* __restrict__ b1,
    const float* __restrict__ b2, const float* __restrict__ b3,
    ushort* __restrict__ hid, int m0)
{
    __shared__ ushort sA[128 * 64];  // 16 KB, byte-swizzled
    char* sAb = reinterpret_cast<char*>(sA);

    int tid = threadIdx.x;
    int l = tid & 63, w = tid >> 6;
    int wm = w >> 1, wn = w & 1;
    int lr = l & 15, lg = l >> 4;
    int nt = blockIdx.x, mt = blockIdx.y;

    // per-lane biases for the 4 n-frags this lane owns
    float bias[4];
#pragma unroll
    for (int nf = 0; nf < 4; ++nf) {
        int n = nt * 128 + wn * 64 + nf * 16 + lr;
        int j = n >> 8, cc = n & 255;
        const float* bp = (j == 0) ? b0 : (j == 1) ? b1 : (j == 2) ? b2 : b3;
        bias[nf] = bp[cc];
    }

    f32x4 acc[4][4] = {};
    const float* Srow = S + (size_t)(m0 + mt * 128) * 512;

    for (int it = 0; it < 8; ++it) {
        __syncthreads();
        // stage S tile [128][64] fp32 -> bf16 (coalesced 32B/lane reads)
#pragma unroll
        for (int i = 0; i < 4; ++i) {
            int idx = i * 256 + tid;
            int m = idx >> 3, kc = idx & 7;
            const float4* g = reinterpret_cast<const float4*>(
                Srow + (size_t)m * 512 + it * 64 + kc * 8);
            float4 fa = g[0], fb = g[1];
            ushort8 o;
            o[0] = f2bf(fa.x); o[1] = f2bf(fa.y); o[2] = f2bf(fa.z); o[3] = f2bf(fa.w);
            o[4] = f2bf(fb.x); o[5] = f2bf(fb.y); o[6] = f2bf(fb.z); o[7] = f2bf(fb.w);
            int off = (m * 128 + kc * 16) ^ ((m & 7) << 4);
            *reinterpret_cast<ushort8*>(sAb + off) = o;
        }
        __syncthreads();

#pragma unroll
        for (int ks = 0; ks < 2; ++ks) {
            bf16x8 a[4];
#pragma unroll
            for (int mf = 0; mf < 4; ++mf) {
                int m = wm * 64 + mf * 16 + lr;
                int off = (m * 128 + (ks * 32 + lg * 8) * 2) ^ ((m & 7) << 4);
                a[mf] = *reinterpret_cast<const bf16x8*>(sAb + off);
            }
            bf16x8 b[4];
#pragma unroll
            for (int nf = 0; nf < 4; ++nf) {
                int n16 = nt * 8 + wn * 4 + nf;
                size_t off = ((size_t)(n16 * 16 + it * 2 + ks) * 64 + l) * 8;
                b[nf] = *reinterpret_cast<const bf16x8*>(W1p + off);
            }
#pragma unroll
            for (int nf = 0; nf < 4; ++nf)
#pragma unroll
                for (int mf = 0; mf < 4; ++mf)
                    acc[mf][nf] = __builtin_amdgcn_mfma_f32_16x16x32_bf16(
                        a[mf], b[nf], acc[mf][nf], 0, 0, 0);
        }
    }

    // epilogue: bias + relu -> bf16, via LDS transpose, two 64-col halves
    for (int h = 0; h < 2; ++h) {
        __syncthreads();
        if (wn == h) {
#pragma unroll
            for (int mf = 0; mf < 4; ++mf)
#pragma unroll
                for (int nf = 0; nf < 4; ++nf)
#pragma unroll
                    for (int r = 0; r < 4; ++r) {
                        float v = acc[mf][nf][r] + bias[nf];
                        v = v > 0.f ? v : 0.f;
                        sA[(wm * 64 + mf * 16 + lg * 4 + r) * 64 + nf * 16 + lr] = f2bf(v);
                    }
        }
        __syncthreads();
#pragma unroll
        for (int i = 0; i < 4; ++i) {
            int idx = i * 256 + tid;
            int m = idx >> 3, c8 = idx & 7;
            ushort8 o = *reinterpret_cast<const ushort8*>(sA + m * 64 + c8 * 8);
            *reinterpret_cast<ushort8*>(
                hid + (size_t)(mt * 128 + m) * 1024 + nt * 128 + h * 64 + c8 * 8) = o;
        }
    }
}

// ---------------------------------------------------------------------------
// Layer-2 (4 block GEMMs via MFMA) + mixer, fused. 32 samples / wg.
// 21 output n-frags (321 cols padded to 336) split 6/6/5/4 over 4 waves.
// ---------------------------------------------------------------------------
__global__ __launch_bounds__(256) void k_l2mix(
    const ushort* __restrict__ hid, const ushort* __restrict__ W2p,
    const float* __restrict__ bw1, const float* __restrict__ bb1,
    const float* __restrict__ bw2, const float* __restrict__ bb2,
    const float* __restrict__ q, float* __restrict__ out, int m0)
{
    __shared__ float sO[32 * 336];  // 43 KB
    int tid = threadIdx.x, l = tid & 63, w = tid >> 6;
    int lr = l & 15, lg = l >> 4;
    int sb = blockIdx.x * 32;

    const int fs[5] = {0, 6, 12, 17, 21};
    int jloaded = -1;
    bf16x8 a[2][8];
    for (int f = fs[w]; f < fs[w + 1]; ++f) {
        int j = (f < 12) ? 0 : (f < 16) ? 1 : (f < 20) ? 2 : 3;
        if (j != jloaded) {
#pragma unroll
            for (int mf = 0; mf < 2; ++mf)
#pragma unroll
                for (int ks = 0; ks < 8; ++ks)
                    a[mf][ks] = *reinterpret_cast<const bf16x8*>(
                        hid + (size_t)(sb + mf * 16 + lr) * 1024 + j * 256 + ks * 32 + lg * 8);
            jloaded = j;
        }
        f32x4 acc[2] = {};
#pragma unroll
        for (int ks = 0; ks < 8; ++ks) {
            bf16x8 b = *reinterpret_cast<const bf16x8*>(W2p + ((size_t)(f * 8 + ks) * 64 + l) * 8);
            acc[0] = __builtin_amdgcn_mfma_f32_16x16x32_bf16(a[0][ks], b, acc[0], 0, 0, 0);
            acc[1] = __builtin_amdgcn_mfma_f32_16x16x32_bf16(a[1][ks], b, acc[1], 0, 0, 0);
        }
        int colg = f * 16 + lr;
        float bv = 0.f; bool doabs = false;
        if (colg < 192)       { bv = bw1[colg];       doabs = true; }
        else if (colg < 256)  { bv = bb1[colg - 192]; doabs = false; }
        else if (colg < 320)  { bv = bw2[colg - 256]; doabs = true; }
        else if (colg == 320) { bv = bb2[0];          doabs = false; }
#pragma unroll
        for (int mf = 0; mf < 2; ++mf)
#pragma unroll
            for (int r = 0; r < 4; ++r) {
                float v = acc[mf][r] + bv;
                if (doabs) v = fabsf(v);
                sO[(mf * 16 + lg * 4 + r) * 336 + colg] = v;
            }
    }
    __syncthreads();

    // mixer: 8 threads per sample, each covers 8 of the 64 hidden units
    int sm = tid >> 3, oct = tid & 7;
    const float* qs = q + (size_t)(m0 + sb + sm) * 3;
    float q0 = qs[0], q1 = qs[1], q2 = qs[2];
    const float* ob = sO + sm * 336;
    float res[3];
#pragma unroll
    for (int n = 0; n < 3; ++n) {
        float qa, qb, qc;
        if (n == 0)      { qa = q0; qb = q1; qc = q2; }
        else if (n == 1) { qa = q1; qb = q0; qc = q2; }
        else             { qa = q2; qb = q0; qc = q1; }
        float accm = 0.f;
#pragma unroll
        for (int hh = 0; hh < 8; ++hh) {
            int hc = oct * 8 + hh;
            float hv = ob[192 + hc] + qa * ob[hc] + qb * ob[64 + hc] + qc * ob[128 + hc];
            float ev = hv > 0.f ? hv : expm1f(hv);
            accm += ev * ob[256 + hc];
        }
        accm += __shfl_xor(accm, 1);
        accm += __shfl_xor(accm, 2);
        accm += __shfl_xor(accm, 4);
        res[n] = accm;
    }
    if (oct == 0) {
        float b2v = ob[320];
        float* op = out + (size_t)(m0 + sb + sm) * 3;
        op[0] = res[0] + b2v;
        op[1] = res[1] + b2v;
        op[2] = res[2] + b2v;
    }
}

extern "C" void kernel_launch(void* const* d_in, const int* in_sizes, int n_in,
                              void* d_out, int out_size, void* d_ws, size_t ws_size,
                              hipStream_t stream)
{
    const float* q      = (const float*)d_in[0];
    const float* S      = (const float*)d_in[1];
    const float* hw1_W1 = (const float*)d_in[2];
    const float* hw1_b1 = (const float*)d_in[3];
    const float* hw1_W2 = (const float*)d_in[4];
    const float* hw1_b2 = (const float*)d_in[5];
    const float* hb1_W1 = (const float*)d_in[6];
    const float* hb1_b1 = (const float*)d_in[7];
    const float* hb1_W2 = (const float*)d_in[8];
    const float* hb1_b2 = (const float*)d_in[9];
    const float* hw2_W1 = (const float*)d_in[10];
    const float* hw2_b1 = (const float*)d_in[11];
    const float* hw2_W2 = (const float*)d_in[12];
    const float* hw2_b2 = (const float*)d_in[13];
    const float* hb2_W1 = (const float*)d_in[14];
    const float* hb2_b1 = (const float*)d_in[15];
    const float* hb2_W2 = (const float*)d_in[16];
    const float* hb2_b2 = (const float*)d_in[17];

    int TB = in_sizes[1] / 512;

    ushort* W1p = (ushort*)d_ws;            // 1 MB (65536 chunks * 16 B)
    ushort* W2p = W1p + (size_t)65536 * 8;  // 168 KB
    ushort* hid = W2p + (size_t)10752 * 8;
    size_t used = (size_t)(65536 + 10752) * 16;
    size_t hid_cap = (ws_size > used) ? (ws_size - used) : 0;
    long long max_chunk = (long long)(hid_cap / 2048);  // samples (1024 bf16 each)
    max_chunk &= ~127LL;
    if (max_chunk > TB) max_chunk = TB;
    if (max_chunk < 128) max_chunk = 128;  // best effort

    k_pack<<<dim3(298), dim3(256), 0, stream>>>(
        hw1_W1, hb1_W1, hw2_W1, hb2_W1,
        hw1_W2, hb1_W2, hw2_W2, hb2_W2, W1p, W2p);

    for (int m0 = 0; m0 < TB; m0 += (int)max_chunk) {
        int mc = TB - m0;
        if (mc > max_chunk) mc = (int)max_chunk;
        k_l1<<<dim3(8, mc / 128), dim3(256), 0, stream>>>(
            S, W1p, hw1_b1, hb1_b1, hw2_b1, hb2_b1, hid, m0);
        k_l2mix<<<dim3(mc / 32), dim3(256), 0, stream>>>(
            hid, W2p, hw1_b2, hb1_b2, hw2_b2, hb2_b2, q, (float*)d_out, m0);
    }
}

// Round 2
// 178.979 us; speedup vs baseline: 1.5308x; 1.5308x over previous
//
#include <hip/hip_runtime.h>
#include <hip/hip_bf16.h>

typedef __attribute__((ext_vector_type(8))) __bf16 bf16x8;
typedef __attribute__((ext_vector_type(4))) float f32x4;
typedef __attribute__((ext_vector_type(8))) unsigned short ushort8;
typedef unsigned short ushort;

__device__ __forceinline__ ushort f2bf(float f) {
    unsigned u = __builtin_bit_cast(unsigned, f);
    unsigned r = (u + 0x7fffu + ((u >> 16) & 1u)) >> 16;
    return (ushort)r;
}

__device__ __forceinline__ unsigned cvtpk(float a, float b) {
    unsigned r;
    asm("v_cvt_pk_bf16_f32 %0, %1, %2" : "=v"(r) : "v"(a), "v"(b));
    return r;
}

// ---------------------------------------------------------------------------
// Pack layer-1 weights (4x [512,256] fp32) and layer-2 weights into bf16
// MFMA-B-fragment order in ws. (unchanged from R0)
// W1p chunk c = (n16*16 + ksg)*64 + lane ; element e: B[k=ksg*32+(l>>4)*8+e][col=(n16&15)*16+(l&15)] of hypernet j=n16>>4
// W2p chunk c = (f*8 + ks)*64 + lane over 21 n-frags (321 cols padded to 336)
// ---------------------------------------------------------------------------
__global__ __launch_bounds__(256) void k_pack(
    const float* __restrict__ w1a, const float* __restrict__ w1b,
    const float* __restrict__ w1c, const float* __restrict__ w1d,
    const float* __restrict__ w2a, const float* __restrict__ w2b,
    const float* __restrict__ w2c, const float* __restrict__ w2d,
    ushort* __restrict__ W1p, ushort* __restrict__ W2p)
{
    int c = blockIdx.x * 256 + threadIdx.x;
    if (c < 65536) {
        int l = c & 63, ks = (c >> 6) & 15, n16 = c >> 10;
        int j = n16 >> 4;
        int col = (n16 & 15) * 16 + (l & 15);
        int kb = ks * 32 + (l >> 4) * 8;
        const float* W = (j == 0) ? w1a : (j == 1) ? w1b : (j == 2) ? w1c : w1d;
        ushort8 o;
#pragma unroll
        for (int e = 0; e < 8; ++e) o[e] = f2bf(W[(size_t)(kb + e) * 256 + col]);
        *reinterpret_cast<ushort8*>(W1p + (size_t)c * 8) = o;
    } else if (c < 65536 + 10752) {
        int cc = c - 65536;
        int l = cc & 63, ks = (cc >> 6) & 7, f = cc >> 9;
        int colg = f * 16 + (l & 15);
        int kb = ks * 32 + (l >> 4) * 8;
        const float* W = nullptr; int lc = 0, ncols = 1;
        if (colg < 192)        { W = w2a; lc = colg;       ncols = 192; }
        else if (colg < 256)   { W = w2b; lc = colg - 192; ncols = 64; }
        else if (colg < 320)   { W = w2c; lc = colg - 256; ncols = 64; }
        else if (colg == 320)  { W = w2d; lc = 0;          ncols = 1; }
        ushort8 o;
#pragma unroll
        for (int e = 0; e < 8; ++e)
            o[e] = W ? f2bf(W[(size_t)(kb + e) * ncols + lc]) : (ushort)0;
        *reinterpret_cast<ushort8*>(W2p + (size_t)cc * 8) = o;
    }
}

// ---------------------------------------------------------------------------
// Layer-1 GEMM v2: block = 64 rows x all 1024 cols. S staged ONCE into 64 KB
// XOR-swizzled LDS via v_cvt_pk_bf16_f32; wave w owns cols [w*256, w*256+256)
// (exactly hypernet j=w). B-frags read directly from L2-resident packed W1p.
// Single __syncthreads; per-wave private LDS slice for coalesced epilogue.
// ---------------------------------------------------------------------------
__global__ __launch_bounds__(256) void k_l1(
    const float* __restrict__ S, const ushort* __restrict__ W1p,
    const float* __restrict__ b0, const float* __restrict__ b1,
    const float* __restrict__ b2, const float* __restrict__ b3,
    ushort* __restrict__ hid, int m0)
{
    __shared__ ushort sA[64 * 512];     // 64 KB, 16B-granule XOR swizzle
    __shared__ ushort sT[4][64 * 32];   // 16 KB, per-wave transpose slice
    char* sAb = reinterpret_cast<char*>(sA);

    int tid = threadIdx.x, l = tid & 63, w = tid >> 6;
    int lr = l & 15, lg = l >> 4;
    int mt = blockIdx.x;
    const float* Srow = S + (size_t)(m0 + mt * 64) * 512;

    // ---- stage S[64][512] fp32 -> bf16, swizzled: addr16 = row*64 + (kc ^ (row&7))
#pragma unroll
    for (int i = 0; i < 16; ++i) {
        int c = i * 256 + tid;
        int row = c >> 6, kc = c & 63;
        const float4* g = reinterpret_cast<const float4*>(Srow + (size_t)row * 512 + kc * 8);
        float4 fa = g[0], fb = g[1];
        uint4 o;
        o.x = cvtpk(fa.x, fa.y); o.y = cvtpk(fa.z, fa.w);
        o.z = cvtpk(fb.x, fb.y); o.w = cvtpk(fb.z, fb.w);
        *reinterpret_cast<uint4*>(sAb + (size_t)(row * 64 + (kc ^ (row & 7))) * 16) = o;
    }
    __syncthreads();

    const float* bp = (w == 0) ? b0 : (w == 1) ? b1 : (w == 2) ? b2 : b3;
    ushort* myT = sT[w];

    for (int cg = 0; cg < 4; ++cg) {
        f32x4 acc[4][4] = {{{0.f}}};
        for (int it = 0; it < 8; ++it) {
#pragma unroll
            for (int ks = 0; ks < 2; ++ks) {
                bf16x8 a[4];
#pragma unroll
                for (int mf = 0; mf < 4; ++mf) {
                    int row = mf * 16 + lr;
                    int kc = it * 8 + ks * 4 + lg;
                    a[mf] = *reinterpret_cast<const bf16x8*>(
                        sAb + (size_t)(row * 64 + (kc ^ (row & 7))) * 16);
                }
#pragma unroll
                for (int nf = 0; nf < 4; ++nf) {
                    int n16 = w * 16 + cg * 4 + nf;
                    bf16x8 b = *reinterpret_cast<const bf16x8*>(
                        W1p + ((size_t)(n16 * 16 + it * 2 + ks) * 64 + l) * 8);
#pragma unroll
                    for (int mf = 0; mf < 4; ++mf)
                        acc[mf][nf] = __builtin_amdgcn_mfma_f32_16x16x32_bf16(
                            a[mf], b, acc[mf][nf], 0, 0, 0);
                }
            }
        }
        // ---- epilogue: bias+relu -> bf16, two 32-col halves via private slice
        int colbase = w * 256 + cg * 64;
        for (int h = 0; h < 2; ++h) {
            asm volatile("s_waitcnt lgkmcnt(0)" ::: "memory");  // WAR vs prior readback
#pragma unroll
            for (int nf2 = 0; nf2 < 2; ++nf2) {
                int nf = h * 2 + nf2;
                float bv = bp[(colbase + nf * 16 + lr) & 255];
#pragma unroll
                for (int mf = 0; mf < 4; ++mf)
#pragma unroll
                    for (int r = 0; r < 4; ++r) {
                        float v = acc[mf][nf][r] + bv;
                        v = v > 0.f ? v : 0.f;
                        myT[(mf * 16 + lg * 4 + r) * 32 + nf2 * 16 + lr] = f2bf(v);
                    }
            }
            asm volatile("s_waitcnt lgkmcnt(0)" ::: "memory");  // writes done before readback
#pragma unroll
            for (int i = 0; i < 4; ++i) {
                int id = i * 64 + l;
                int row = id >> 2, c8 = id & 3;
                ushort8 o = *reinterpret_cast<const ushort8*>(myT + row * 32 + c8 * 8);
                *reinterpret_cast<ushort8*>(
                    hid + (size_t)(mt * 64 + row) * 1024 + colbase + h * 32 + c8 * 8) = o;
            }
        }
    }
}

// ---------------------------------------------------------------------------
// Layer-2 (4 block GEMMs via MFMA) + mixer, fused. 32 samples / wg.
// (unchanged from R0)
// ---------------------------------------------------------------------------
__global__ __launch_bounds__(256) void k_l2mix(
    const ushort* __restrict__ hid, const ushort* __restrict__ W2p,
    const float* __restrict__ bw1, const float* __restrict__ bb1,
    const float* __restrict__ bw2, const float* __restrict__ bb2,
    const float* __restrict__ q, float* __restrict__ out, int m0)
{
    __shared__ float sO[32 * 336];  // 43 KB
    int tid = threadIdx.x, l = tid & 63, w = tid >> 6;
    int lr = l & 15, lg = l >> 4;
    int sb = blockIdx.x * 32;

    const int fs[5] = {0, 6, 12, 17, 21};
    int jloaded = -1;
    bf16x8 a[2][8];
    for (int f = fs[w]; f < fs[w + 1]; ++f) {
        int j = (f < 12) ? 0 : (f < 16) ? 1 : (f < 20) ? 2 : 3;
        if (j != jloaded) {
#pragma unroll
            for (int mf = 0; mf < 2; ++mf)
#pragma unroll
                for (int ks = 0; ks < 8; ++ks)
                    a[mf][ks] = *reinterpret_cast<const bf16x8*>(
                        hid + (size_t)(sb + mf * 16 + lr) * 1024 + j * 256 + ks * 32 + lg * 8);
            jloaded = j;
        }
        f32x4 acc[2] = {};
#pragma unroll
        for (int ks = 0; ks < 8; ++ks) {
            bf16x8 b = *reinterpret_cast<const bf16x8*>(W2p + ((size_t)(f * 8 + ks) * 64 + l) * 8);
            acc[0] = __builtin_amdgcn_mfma_f32_16x16x32_bf16(a[0][ks], b, acc[0], 0, 0, 0);
            acc[1] = __builtin_amdgcn_mfma_f32_16x16x32_bf16(a[1][ks], b, acc[1], 0, 0, 0);
        }
        int colg = f * 16 + lr;
        float bv = 0.f; bool doabs = false;
        if (colg < 192)       { bv = bw1[colg];       doabs = true; }
        else if (colg < 256)  { bv = bb1[colg - 192]; doabs = false; }
        else if (colg < 320)  { bv = bw2[colg - 256]; doabs = true; }
        else if (colg == 320) { bv = bb2[0];          doabs = false; }
#pragma unroll
        for (int mf = 0; mf < 2; ++mf)
#pragma unroll
            for (int r = 0; r < 4; ++r) {
                float v = acc[mf][r] + bv;
                if (doabs) v = fabsf(v);
                sO[(mf * 16 + lg * 4 + r) * 336 + colg] = v;
            }
    }
    __syncthreads();

    // mixer: 8 threads per sample, each covers 8 of the 64 hidden units
    int sm = tid >> 3, oct = tid & 7;
    const float* qs = q + (size_t)(m0 + sb + sm) * 3;
    float q0 = qs[0], q1 = qs[1], q2 = qs[2];
    const float* ob = sO + sm * 336;
    float res[3];
#pragma unroll
    for (int n = 0; n < 3; ++n) {
        float qa, qb, qc;
        if (n == 0)      { qa = q0; qb = q1; qc = q2; }
        else if (n == 1) { qa = q1; qb = q0; qc = q2; }
        else             { qa = q2; qb = q0; qc = q1; }
        float accm = 0.f;
#pragma unroll
        for (int hh = 0; hh < 8; ++hh) {
            int hc = oct * 8 + hh;
            float hv = ob[192 + hc] + qa * ob[hc] + qb * ob[64 + hc] + qc * ob[128 + hc];
            float ev = hv > 0.f ? hv : expm1f(hv);
            accm += ev * ob[256 + hc];
        }
        accm += __shfl_xor(accm, 1);
        accm += __shfl_xor(accm, 2);
        accm += __shfl_xor(accm, 4);
        res[n] = accm;
    }
    if (oct == 0) {
        float b2v = ob[320];
        float* op = out + (size_t)(m0 + sb + sm) * 3;
        op[0] = res[0] + b2v;
        op[1] = res[1] + b2v;
        op[2] = res[2] + b2v;
    }
}

extern "C" void kernel_launch(void* const* d_in, const int* in_sizes, int n_in,
                              void* d_out, int out_size, void* d_ws, size_t ws_size,
                              hipStream_t stream)
{
    const float* q      = (const float*)d_in[0];
    const float* S      = (const float*)d_in[1];
    const float* hw1_W1 = (const float*)d_in[2];
    const float* hw1_b1 = (const float*)d_in[3];
    const float* hw1_W2 = (const float*)d_in[4];
    const float* hw1_b2 = (const float*)d_in[5];
    const float* hb1_W1 = (const float*)d_in[6];
    const float* hb1_b1 = (const float*)d_in[7];
    const float* hb1_W2 = (const float*)d_in[8];
    const float* hb1_b2 = (const float*)d_in[9];
    const float* hw2_W1 = (const float*)d_in[10];
    const float* hw2_b1 = (const float*)d_in[11];
    const float* hw2_W2 = (const float*)d_in[12];
    const float* hw2_b2 = (const float*)d_in[13];
    const float* hb2_W1 = (const float*)d_in[14];
    const float* hb2_b1 = (const float*)d_in[15];
    const float* hb2_W2 = (const float*)d_in[16];
    const float* hb2_b2 = (const float*)d_in[17];

    int TB = in_sizes[1] / 512;

    ushort* W1p = (ushort*)d_ws;            // 1 MB (65536 chunks * 16 B)
    ushort* W2p = W1p + (size_t)65536 * 8;  // 168 KB
    ushort* hid = W2p + (size_t)10752 * 8;
    size_t used = (size_t)(65536 + 10752) * 16;
    size_t hid_cap = (ws_size > used) ? (ws_size - used) : 0;
    long long max_chunk = (long long)(hid_cap / 2048);  // samples (1024 bf16 each)
    max_chunk &= ~127LL;
    if (max_chunk > TB) max_chunk = TB;
    if (max_chunk < 128) max_chunk = 128;  // best effort

    k_pack<<<dim3(298), dim3(256), 0, stream>>>(
        hw1_W1, hb1_W1, hw2_W1, hb2_W1,
        hw1_W2, hb1_W2, hw2_W2, hb2_W2, W1p, W2p);

    for (int m0 = 0; m0 < TB; m0 += (int)max_chunk) {
        int mc = TB - m0;
        if (mc > max_chunk) mc = (int)max_chunk;
        k_l1<<<dim3(mc / 64), dim3(256), 0, stream>>>(
            S, W1p, hw1_b1, hb1_b1, hw2_b1, hb2_b1, hid, m0);
        k_l2mix<<<dim3(mc / 32), dim3(256), 0, stream>>>(
            hid, W2p, hw1_b2, hb1_b2, hw2_b2, hb2_b2, q, (float*)d_out, m0);
    }
}